// Round 12
// baseline (37100.665 us; speedup 1.0000x reference)
//
#include <hip/hip_runtime.h>

typedef __attribute__((ext_vector_type(8))) __bf16 bf16x8;
typedef __attribute__((ext_vector_type(4))) float f32x4;

#define DEV __device__ __forceinline__

DEV unsigned short f2bf(float f) {
  unsigned int u = __float_as_uint(f);
  u += 0x7FFFu + ((u >> 16) & 1u);   // RNE
  return (unsigned short)(u >> 16);
}

// ---------------- kernel 1: f32 -> bf16 (vectorized) ----------------
__global__ __launch_bounds__(256) void k_f32_to_bf16(const float* __restrict__ x,
                                                     unsigned short* __restrict__ y) {
  size_t i = ((size_t)blockIdx.x * 256 + threadIdx.x) * 8;
  float4 a = *(const float4*)(x + i);
  float4 b = *(const float4*)(x + i + 4);
  union { unsigned short u[8]; uint4 v; } o;
  o.u[0] = f2bf(a.x); o.u[1] = f2bf(a.y); o.u[2] = f2bf(a.z); o.u[3] = f2bf(a.w);
  o.u[4] = f2bf(b.x); o.u[5] = f2bf(b.y); o.u[6] = f2bf(b.z); o.u[7] = f2bf(b.w);
  *(uint4*)(y + i) = o.v;
}

// ------- kernel 2: AWQ int4 dequant -> W^T bf16 [N][K] (LDS transpose) -------
__global__ __launch_bounds__(256) void k_dequant_t(const int* __restrict__ qw,
                                                   const int* __restrict__ qz,
                                                   const float* __restrict__ sc,
                                                   unsigned short* __restrict__ wt,
                                                   int K, int N) {
  __shared__ __align__(16) unsigned short st[64][72];
  const int k0 = blockIdx.x * 64, n0 = blockIdx.y * 64;
  const int t = threadIdx.x;
  const int g = k0 >> 7;
  const int Np = N >> 3;
#pragma unroll
  for (int it = 0; it < 2; ++it) {
    int idx = t + it * 256;
    int k = idx >> 3;
    int nc = idx & 7;
    unsigned int w = (unsigned int)qw[(size_t)(k0 + k) * Np + (n0 >> 3) + nc];
    unsigned int z = (unsigned int)qz[(size_t)g * Np + (n0 >> 3) + nc];
#pragma unroll
    for (int i = 0; i < 8; ++i) {
      float s = sc[(size_t)g * N + n0 + nc * 8 + i];
      float v = ((float)(int)((w >> (4 * i)) & 0xFu) -
                 (float)(int)((z >> (4 * i)) & 0xFu)) * s;
      st[nc * 8 + i][k] = f2bf(v);
    }
  }
  __syncthreads();
  const int n = t >> 2, c = t & 3;
  uint4 v0 = *(const uint4*)&st[n][c * 16];
  uint4 v1 = *(const uint4*)&st[n][c * 16 + 8];
  unsigned short* dst = wt + (size_t)(n0 + n) * K + k0 + c * 16;
  *(uint4*)dst = v0;
  *(uint4*)(dst + 8) = v1;
}

// ------ kernel 3: 256x256 GEMM, 2-slab ring + reg-dbuf, 2 blocks/CU ----------
// R11 post-mortem: A-from-global refuted (scattered 64B reads, 2x slower).
// R8 budget (corrected model): half-slab = 2790 cyc = MFMA 1240 + LDS 1500
// SERIALIZED -- with 1 block/CU (128KB ring) nothing fills either pipe's idle
// window. Fix: ring 4->2 slabs (A,B: 2x16KB each = 64KB LDS) -> 2 blocks/CU;
// sibling block's MFMA covers this block's LDS/sync stalls (m114/m97 pattern).
// Sync per half-top: lgkmcnt(0) + vmcnt(0) + barrier -- fully order-robust
// (R10 lesson: no ledger fragility), lgkm(0) closes the cross-wave
// ds_read-vs-DMA-overwrite hazard on slot reuse.
// Reg-dbuf frags: MFMA(h) overlaps ds_read(h+1) issue; stage slab h+2 into
// the slot just freed by the frags now in registers.

#define STAGE_A(h) do { const unsigned short* g_ = A + gsA + (size_t)(h) * 32;               \
  __builtin_amdgcn_global_load_lds((const __attribute__((address_space(1))) void*)g_,        \
      (__attribute__((address_space(3))) void*)(&sA[(h) & 1][0] + tid * 8), 16, 0, 0);       \
  __builtin_amdgcn_global_load_lds((const __attribute__((address_space(1))) void*)(g_ + (size_t)128 * K), \
      (__attribute__((address_space(3))) void*)(&sA[(h) & 1][4096] + tid * 8), 16, 0, 0); } while (0)
#define STAGE_B(h) do { const unsigned short* g_ = B + gsB + (size_t)(h) * 32;               \
  __builtin_amdgcn_global_load_lds((const __attribute__((address_space(1))) void*)g_,        \
      (__attribute__((address_space(3))) void*)(&sB[(h) & 1][0] + tid * 8), 16, 0, 0);       \
  __builtin_amdgcn_global_load_lds((const __attribute__((address_space(1))) void*)(g_ + (size_t)128 * K), \
      (__attribute__((address_space(3))) void*)(&sB[(h) & 1][4096] + tid * 8), 16, 0, 0); } while (0)

#define LDA(s, m) (*(const bf16x8*)((const char*)&sA[s][0] + offA + (m) * 1024))
#define LDB(s, n) (*(const bf16x8*)((const char*)&sB[s][0] + offB + (n) * 1024))

template <int GELU>
__global__ __launch_bounds__(512, 4) void k_gemm256(const unsigned short* __restrict__ A,
                                                    const unsigned short* __restrict__ B,
                                                    void* __restrict__ C,
                                                    int M, int N, int K) {
  __shared__ __align__(16) unsigned short sA[2][8192];
  __shared__ __align__(16) unsigned short sB[2][8192];
  const int tid = threadIdx.x;
  const int lane = tid & 63;
  const int wave = tid >> 6;
  const int wm = wave >> 2, wn = wave & 3;
  const int r16 = lane & 15, q = lane >> 4;

  // Raster: bijective XCD chunk + grouped-m (GM=16, m-fastest within group).
  const int nbx = N >> 8;
  const int cpx = gridDim.x >> 3;
  const int g = (blockIdx.x & 7) * cpx + (blockIdx.x >> 3);
  const int gw = nbx << 4;
  const int grp = g / gw;
  const int rem = g - grp * gw;
  const int m0 = (grp * 16 + (rem & 15)) * 256;
  const int n0 = (rem >> 4) * 256;

  const int rA = wm * 128 + r16;
  const int rB = wn * 64 + r16;
  const int offA = rA * 64 + ((q * 16) ^ (((rA >> 1) & 3) << 4));
  const int offB = rB * 64 + ((q * 16) ^ (((rB >> 1) & 3) << 4));

  const int sr = tid >> 2;                        // staging row (0..127)
  const int ssrc = (tid & 3) ^ ((sr >> 1) & 3);   // pre-swizzled global 16B slot
  const size_t gsA = (size_t)(m0 + sr) * K + (size_t)ssrc * 8;
  const size_t gsB = (size_t)(n0 + sr) * K + (size_t)ssrc * 8;

  f32x4 acc[8][4] = {};
  bf16x8 pA0[8], pB0[4], pA1[8], pB1[4];
  const int NT = K >> 6;

  // prologue: stage slabs 0 (slot0) and 1 (slot1); full drain; read frags(0)
  STAGE_A(0); STAGE_B(0); STAGE_A(1); STAGE_B(1);
  asm volatile("s_waitcnt vmcnt(0)" ::: "memory");
  __builtin_amdgcn_s_barrier();
#pragma unroll
  for (int i = 0; i < 8; ++i) pA0[i] = LDA(0, i);
#pragma unroll
  for (int j = 0; j < 4; ++j) pB0[j] = LDB(0, j);

  for (int t = 0; t < NT; ++t) {
    // ---- even half h=2t: MFMA p0; read frags(2t+1) slot1 -> p1; stage 2t+2 slot0
    asm volatile("s_waitcnt vmcnt(0) lgkmcnt(0)" ::: "memory");
    __builtin_amdgcn_s_barrier();
#pragma unroll
    for (int i = 0; i < 8; ++i) pA1[i] = LDA(1, i);
#pragma unroll
    for (int j = 0; j < 4; ++j) pB1[j] = LDB(1, j);
    if (t < NT - 1) { STAGE_A(2 * t + 2); STAGE_B(2 * t + 2); }
    __builtin_amdgcn_s_setprio(1);
#pragma unroll
    for (int i = 0; i < 8; ++i)
#pragma unroll
      for (int j = 0; j < 4; ++j)
        acc[i][j] = __builtin_amdgcn_mfma_f32_16x16x32_bf16(pA0[i], pB0[j], acc[i][j], 0, 0, 0);
    __builtin_amdgcn_s_setprio(0);

    // ---- odd half h=2t+1: MFMA p1; read frags(2t+2) slot0 -> p0; stage 2t+3 slot1
    asm volatile("s_waitcnt vmcnt(0) lgkmcnt(0)" ::: "memory");
    __builtin_amdgcn_s_barrier();
    if (t < NT - 1) {
#pragma unroll
      for (int i = 0; i < 8; ++i) pA0[i] = LDA(0, i);
#pragma unroll
      for (int j = 0; j < 4; ++j) pB0[j] = LDB(0, j);
      STAGE_A(2 * t + 3); STAGE_B(2 * t + 3);
    }
    __builtin_amdgcn_s_setprio(1);
#pragma unroll
    for (int i = 0; i < 8; ++i)
#pragma unroll
      for (int j = 0; j < 4; ++j)
        acc[i][j] = __builtin_amdgcn_mfma_f32_16x16x32_bf16(pA1[i], pB1[j], acc[i][j], 0, 0, 0);
    __builtin_amdgcn_s_setprio(0);
  }

  // epilogue: C/D layout col=lane&15, row=(lane>>4)*4+reg
  const int mb = m0 + wm * 128 + q * 4;
  const int nb = n0 + wn * 64 + r16;
#pragma unroll
  for (int i = 0; i < 8; ++i) {
#pragma unroll
    for (int j = 0; j < 4; ++j) {
#pragma unroll
      for (int r = 0; r < 4; ++r) {
        int row = mb + i * 16 + r;
        int col = nb + j * 16;
        float v = acc[i][j][r];
        if (GELU) {
          v = 0.5f * v * (1.0f + erff(v * 0.70710678118654752440f));
          ((unsigned short*)C)[(size_t)row * N + col] = f2bf(v);
        } else {
          ((float*)C)[(size_t)row * N + col] = v;
        }
      }
    }
  }
}

extern "C" void kernel_launch(void* const* d_in, const int* in_sizes, int n_in,
                              void* d_out, int out_size, void* d_ws, size_t ws_size,
                              hipStream_t stream) {
  const float* x  = (const float*)d_in[0];
  const int* uqw  = (const int*)d_in[1];
  const int* uqz  = (const int*)d_in[2];
  const float* usc = (const float*)d_in[3];
  const int* dqw  = (const int*)d_in[4];
  const int* dqz  = (const int*)d_in[5];
  const float* dsc = (const float*)d_in[6];
  float* out = (float*)d_out;

  const int T = 8192, D = 4096, F = 16384;
  char* ws = (char*)d_ws;
  unsigned short* xb = (unsigned short*)ws;                                  // 64 MiB
  unsigned short* h  = (unsigned short*)(ws + (size_t)T * D * 2);            // 256 MiB
  unsigned short* wt = (unsigned short*)(ws + (size_t)T * D * 2 + (size_t)T * F * 2); // 128 MiB

  k_f32_to_bf16<<<dim3((T * D) / (256 * 8)), 256, 0, stream>>>(x, xb);
  k_dequant_t<<<dim3(D / 64, F / 64), 256, 0, stream>>>(uqw, uqz, usc, wt, D, F);
  k_gemm256<1><<<dim3((T / 256) * (F / 256)), 512, 0, stream>>>(xb, wt, (void*)h, T, F, D);
  k_dequant_t<<<dim3(F / 64, D / 64), 256, 0, stream>>>(dqw, dqz, dsc, wt, F, D);
  k_gemm256<0><<<dim3((T / 256) * (D / 256)), 512, 0, stream>>>(h, wt, (void*)out, T, D, F);
}

// Round 14
// 2440.157 us; speedup vs baseline: 15.2042x; 15.2042x over previous
//
#include <hip/hip_runtime.h>

typedef __attribute__((ext_vector_type(8))) __bf16 bf16x8;
typedef __attribute__((ext_vector_type(4))) float f32x4;

#define DEV __device__ __forceinline__

DEV unsigned short f2bf(float f) {
  unsigned int u = __float_as_uint(f);
  u += 0x7FFFu + ((u >> 16) & 1u);   // RNE
  return (unsigned short)(u >> 16);
}

// ---------------- kernel 1: f32 -> bf16 (vectorized) ----------------
__global__ __launch_bounds__(256) void k_f32_to_bf16(const float* __restrict__ x,
                                                     unsigned short* __restrict__ y) {
  size_t i = ((size_t)blockIdx.x * 256 + threadIdx.x) * 8;
  float4 a = *(const float4*)(x + i);
  float4 b = *(const float4*)(x + i + 4);
  union { unsigned short u[8]; uint4 v; } o;
  o.u[0] = f2bf(a.x); o.u[1] = f2bf(a.y); o.u[2] = f2bf(a.z); o.u[3] = f2bf(a.w);
  o.u[4] = f2bf(b.x); o.u[5] = f2bf(b.y); o.u[6] = f2bf(b.z); o.u[7] = f2bf(b.w);
  *(uint4*)(y + i) = o.v;
}

// ------- kernel 2: AWQ int4 dequant -> W^T bf16 [N][K] (LDS transpose) -------
__global__ __launch_bounds__(256) void k_dequant_t(const int* __restrict__ qw,
                                                   const int* __restrict__ qz,
                                                   const float* __restrict__ sc,
                                                   unsigned short* __restrict__ wt,
                                                   int K, int N) {
  __shared__ __align__(16) unsigned short st[64][72];
  const int k0 = blockIdx.x * 64, n0 = blockIdx.y * 64;
  const int t = threadIdx.x;
  const int g = k0 >> 7;
  const int Np = N >> 3;
#pragma unroll
  for (int it = 0; it < 2; ++it) {
    int idx = t + it * 256;
    int k = idx >> 3;
    int nc = idx & 7;
    unsigned int w = (unsigned int)qw[(size_t)(k0 + k) * Np + (n0 >> 3) + nc];
    unsigned int z = (unsigned int)qz[(size_t)g * Np + (n0 >> 3) + nc];
#pragma unroll
    for (int i = 0; i < 8; ++i) {
      float s = sc[(size_t)g * N + n0 + nc * 8 + i];
      float v = ((float)(int)((w >> (4 * i)) & 0xFu) -
                 (float)(int)((z >> (4 * i)) & 0xFu)) * s;
      st[nc * 8 + i][k] = f2bf(v);
    }
  }
  __syncthreads();
  const int n = t >> 2, c = t & 3;
  uint4 v0 = *(const uint4*)&st[n][c * 16];
  uint4 v1 = *(const uint4*)&st[n][c * 16 + 8];
  unsigned short* dst = wt + (size_t)(n0 + n) * K + k0 + c * 16;
  *(uint4*)dst = v0;
  *(uint4*)(dst + 8) = v1;
}

// ------ kernel 3: 256x256 GEMM, reg-dbuf + DEEP prefetch (R8 + distance 3) ----
// R12 post-mortem: launch_bounds(512,4) capped VGPR at 64 -> full acc spill
// (WRITE 57GB scratch). 2 blocks/CU is VGPR-impossible at this tile. Reverted
// to R8 (52% MfmaUtil). R8's residual serializer: half-top vmcnt(4) waited on
// a DMA staged only ONE half earlier (~500-900 cyc flight-time stall/half).
// This round: prefetch distance 1->3 halves on the same 4-slab ring -- even
// half t stages slab 2t+4 (slot (2t)&3, frag-read last half + barrier-safe),
// odd half stages 2t+5. Whole-half counted waits (order-robust, DMA-only
// vmcnt stream): even-top vmcnt(8) [t<=NT-2], odd-top vmcnt(8) [t<=NT-3] /
// vmcnt(4) [NT-2] / vmcnt(0) [NT-1]. Slot-conflict audit: no outstanding DMA
// targets the slot being frag-read, both halves.

#define STAGE_A(h) do { const unsigned short* g_ = A + gsA + (size_t)(h) * 32;               \
  __builtin_amdgcn_global_load_lds((const __attribute__((address_space(1))) void*)g_,        \
      (__attribute__((address_space(3))) void*)(&sA[(h) & 3][0] + tid * 8), 16, 0, 0);       \
  __builtin_amdgcn_global_load_lds((const __attribute__((address_space(1))) void*)(g_ + (size_t)128 * K), \
      (__attribute__((address_space(3))) void*)(&sA[(h) & 3][4096] + tid * 8), 16, 0, 0); } while (0)
#define STAGE_B(h) do { const unsigned short* g_ = B + gsB + (size_t)(h) * 32;               \
  __builtin_amdgcn_global_load_lds((const __attribute__((address_space(1))) void*)g_,        \
      (__attribute__((address_space(3))) void*)(&sB[(h) & 3][0] + tid * 8), 16, 0, 0);       \
  __builtin_amdgcn_global_load_lds((const __attribute__((address_space(1))) void*)(g_ + (size_t)128 * K), \
      (__attribute__((address_space(3))) void*)(&sB[(h) & 3][4096] + tid * 8), 16, 0, 0); } while (0)

#define LDA(s, m) (*(const bf16x8*)((const char*)&sA[s][0] + offA + (m) * 1024))
#define LDB(s, n) (*(const bf16x8*)((const char*)&sB[s][0] + offB + (n) * 1024))

template <int GELU>
__global__ __launch_bounds__(512, 2) void k_gemm256(const unsigned short* __restrict__ A,
                                                    const unsigned short* __restrict__ B,
                                                    void* __restrict__ C,
                                                    int M, int N, int K) {
  __shared__ __align__(16) unsigned short sA[4][8192];
  __shared__ __align__(16) unsigned short sB[4][8192];
  const int tid = threadIdx.x;
  const int lane = tid & 63;
  const int wave = tid >> 6;
  const int wm = wave >> 2, wn = wave & 3;
  const int r16 = lane & 15, q = lane >> 4;

  // Raster: bijective XCD chunk + grouped-m (GM=16, m-fastest within group).
  const int nbx = N >> 8;
  const int cpx = gridDim.x >> 3;
  const int g = (blockIdx.x & 7) * cpx + (blockIdx.x >> 3);
  const int gw = nbx << 4;
  const int grp = g / gw;
  const int rem = g - grp * gw;
  const int m0 = (grp * 16 + (rem & 15)) * 256;
  const int n0 = (rem >> 4) * 256;

  const int rA = wm * 128 + r16;
  const int rB = wn * 64 + r16;
  const int offA = rA * 64 + ((q * 16) ^ (((rA >> 1) & 3) << 4));
  const int offB = rB * 64 + ((q * 16) ^ (((rB >> 1) & 3) << 4));

  const int sr = tid >> 2;                        // staging row (0..127)
  const int ssrc = (tid & 3) ^ ((sr >> 1) & 3);   // pre-swizzled global 16B slot
  const size_t gsA = (size_t)(m0 + sr) * K + (size_t)ssrc * 8;
  const size_t gsB = (size_t)(n0 + sr) * K + (size_t)ssrc * 8;

  f32x4 acc[8][4] = {};
  bf16x8 pA0[8], pB0[4], pA1[8], pB1[4];
  const int NT = K >> 6;

  // prologue: stage slabs 0..3; full drain (order-robust); read frags(0)
  STAGE_A(0); STAGE_B(0); STAGE_A(1); STAGE_B(1);
  STAGE_A(2); STAGE_B(2); STAGE_A(3); STAGE_B(3);
  asm volatile("s_waitcnt vmcnt(0)" ::: "memory");
  __builtin_amdgcn_s_barrier();
#pragma unroll
  for (int i = 0; i < 8; ++i) pA0[i] = LDA(0, i);
#pragma unroll
  for (int j = 0; j < 4; ++j) pB0[j] = LDB(0, j);

  for (int t = 0; t < NT; ++t) {
    const int s1 = (2 * t + 1) & 3, s2 = (2 * t + 2) & 3;

    // ---- even half: MFMA slab 2t (p0); read frags(2t+1)->p1; stage 2t+4
    if (t <= NT - 2) { asm volatile("s_waitcnt vmcnt(8)" ::: "memory"); }
    else             { asm volatile("s_waitcnt vmcnt(0)" ::: "memory"); }
    __builtin_amdgcn_s_barrier();
#pragma unroll
    for (int i = 0; i < 8; ++i) pA1[i] = LDA(s1, i);
#pragma unroll
    for (int j = 0; j < 4; ++j) pB1[j] = LDB(s1, j);
    if (t <= NT - 3) { STAGE_A(2 * t + 4); STAGE_B(2 * t + 4); }
    __builtin_amdgcn_s_setprio(1);
#pragma unroll
    for (int i = 0; i < 8; ++i)
#pragma unroll
      for (int j = 0; j < 4; ++j)
        acc[i][j] = __builtin_amdgcn_mfma_f32_16x16x32_bf16(pA0[i], pB0[j], acc[i][j], 0, 0, 0);
    __builtin_amdgcn_s_setprio(0);

    // ---- odd half: MFMA slab 2t+1 (p1); read frags(2t+2)->p0; stage 2t+5
    if (t <= NT - 3)      { asm volatile("s_waitcnt vmcnt(8)" ::: "memory"); }
    else if (t == NT - 2) { asm volatile("s_waitcnt vmcnt(4)" ::: "memory"); }
    else                  { asm volatile("s_waitcnt vmcnt(0)" ::: "memory"); }
    __builtin_amdgcn_s_barrier();
    if (t < NT - 1) {
#pragma unroll
      for (int i = 0; i < 8; ++i) pA0[i] = LDA(s2, i);
#pragma unroll
      for (int j = 0; j < 4; ++j) pB0[j] = LDB(s2, j);
    }
    if (t <= NT - 3) { STAGE_A(2 * t + 5); STAGE_B(2 * t + 5); }
    __builtin_amdgcn_s_setprio(1);
#pragma unroll
    for (int i = 0; i < 8; ++i)
#pragma unroll
      for (int j = 0; j < 4; ++j)
        acc[i][j] = __builtin_amdgcn_mfma_f32_16x16x32_bf16(pA1[i], pB1[j], acc[i][j], 0, 0, 0);
    __builtin_amdgcn_s_setprio(0);
  }

  // epilogue: C/D layout col=lane&15, row=(lane>>4)*4+reg
  const int mb = m0 + wm * 128 + q * 4;
  const int nb = n0 + wn * 64 + r16;
#pragma unroll
  for (int i = 0; i < 8; ++i) {
#pragma unroll
    for (int j = 0; j < 4; ++j) {
#pragma unroll
      for (int r = 0; r < 4; ++r) {
        int row = mb + i * 16 + r;
        int col = nb + j * 16;
        float v = acc[i][j][r];
        if (GELU) {
          v = 0.5f * v * (1.0f + erff(v * 0.70710678118654752440f));
          ((unsigned short*)C)[(size_t)row * N + col] = f2bf(v);
        } else {
          ((float*)C)[(size_t)row * N + col] = v;
        }
      }
    }
  }
}

extern "C" void kernel_launch(void* const* d_in, const int* in_sizes, int n_in,
                              void* d_out, int out_size, void* d_ws, size_t ws_size,
                              hipStream_t stream) {
  const float* x  = (const float*)d_in[0];
  const int* uqw  = (const int*)d_in[1];
  const int* uqz  = (const int*)d_in[2];
  const float* usc = (const float*)d_in[3];
  const int* dqw  = (const int*)d_in[4];
  const int* dqz  = (const int*)d_in[5];
  const float* dsc = (const float*)d_in[6];
  float* out = (float*)d_out;

  const int T = 8192, D = 4096, F = 16384;
  char* ws = (char*)d_ws;
  unsigned short* xb = (unsigned short*)ws;                                  // 64 MiB
  unsigned short* h  = (unsigned short*)(ws + (size_t)T * D * 2);            // 256 MiB
  unsigned short* wt = (unsigned short*)(ws + (size_t)T * D * 2 + (size_t)T * F * 2); // 128 MiB

  k_f32_to_bf16<<<dim3((T * D) / (256 * 8)), 256, 0, stream>>>(x, xb);
  k_dequant_t<<<dim3(D / 64, F / 64), 256, 0, stream>>>(uqw, uqz, usc, wt, D, F);
  k_gemm256<1><<<dim3((T / 256) * (F / 256)), 512, 0, stream>>>(xb, wt, (void*)h, T, F, D);
  k_dequant_t<<<dim3(F / 64, D / 64), 256, 0, stream>>>(dqw, dqz, dsc, wt, F, D);
  k_gemm256<0><<<dim3((T / 256) * (D / 256)), 512, 0, stream>>>(h, wt, (void*)out, T, D, F);
}

// Round 15
// 2278.163 us; speedup vs baseline: 16.2853x; 1.0711x over previous
//
#include <hip/hip_runtime.h>

typedef __attribute__((ext_vector_type(8))) __bf16 bf16x8;
typedef __attribute__((ext_vector_type(4))) float f32x4;

#define DEV __device__ __forceinline__

DEV unsigned short f2bf(float f) {
  unsigned int u = __float_as_uint(f);
  u += 0x7FFFu + ((u >> 16) & 1u);   // RNE
  return (unsigned short)(u >> 16);
}

// ---------------- kernel 1: f32 -> bf16 (vectorized) ----------------
__global__ __launch_bounds__(256) void k_f32_to_bf16(const float* __restrict__ x,
                                                     unsigned short* __restrict__ y) {
  size_t i = ((size_t)blockIdx.x * 256 + threadIdx.x) * 8;
  float4 a = *(const float4*)(x + i);
  float4 b = *(const float4*)(x + i + 4);
  union { unsigned short u[8]; uint4 v; } o;
  o.u[0] = f2bf(a.x); o.u[1] = f2bf(a.y); o.u[2] = f2bf(a.z); o.u[3] = f2bf(a.w);
  o.u[4] = f2bf(b.x); o.u[5] = f2bf(b.y); o.u[6] = f2bf(b.z); o.u[7] = f2bf(b.w);
  *(uint4*)(y + i) = o.v;
}

// ------- kernel 2: AWQ int4 dequant -> W^T bf16 [N][K] (LDS transpose) -------
__global__ __launch_bounds__(256) void k_dequant_t(const int* __restrict__ qw,
                                                   const int* __restrict__ qz,
                                                   const float* __restrict__ sc,
                                                   unsigned short* __restrict__ wt,
                                                   int K, int N) {
  __shared__ __align__(16) unsigned short st[64][72];
  const int k0 = blockIdx.x * 64, n0 = blockIdx.y * 64;
  const int t = threadIdx.x;
  const int g = k0 >> 7;
  const int Np = N >> 3;
#pragma unroll
  for (int it = 0; it < 2; ++it) {
    int idx = t + it * 256;
    int k = idx >> 3;
    int nc = idx & 7;
    unsigned int w = (unsigned int)qw[(size_t)(k0 + k) * Np + (n0 >> 3) + nc];
    unsigned int z = (unsigned int)qz[(size_t)g * Np + (n0 >> 3) + nc];
#pragma unroll
    for (int i = 0; i < 8; ++i) {
      float s = sc[(size_t)g * N + n0 + nc * 8 + i];
      float v = ((float)(int)((w >> (4 * i)) & 0xFu) -
                 (float)(int)((z >> (4 * i)) & 0xFu)) * s;
      st[nc * 8 + i][k] = f2bf(v);
    }
  }
  __syncthreads();
  const int n = t >> 2, c = t & 3;
  uint4 v0 = *(const uint4*)&st[n][c * 16];
  uint4 v1 = *(const uint4*)&st[n][c * 16 + 8];
  unsigned short* dst = wt + (size_t)(n0 + n) * K + k0 + c * 16;
  *(uint4*)dst = v0;
  *(uint4*)(dst + 8) = v1;
}

// ------ kernel 3: 256x256 GEMM, ONE sync per K-tile (R8 merged) --------------
// R14 post-mortem: deep prefetch refuted (2342->2440, MfmaUtil 52->42); DMA
// flight exonerated along with raster/FETCH (R3-6), vmcnt depth (R7),
// A-from-global (R11). R8 residual: per-tile 5580 cyc vs ~3000 pipe floor;
// the gap tracks the TWO {vmcnt+barrier} events/tile -- each stalls all 8
// waves of the lone resident block (2 waves/SIMD, no sibling block cover).
// Fix: merge to ONE sync per tile. Body: {vmcnt(0); barrier; read 24 frags
// (slab 2t->p0, 2t+1->p1); stage slabs 2t+2,2t+3 (other 2 ring slots);
// 64 MFMA}. Hazards: read-slots disjoint from stage-slots; overwritten slot
// was MFMA-consumed before this barrier (lgkm); per-wave vmcnt BEFORE barrier
// publishes cross-wave DMA (R10 discipline); flight window = full tile.
// Compiler's fine lgkm waits start p0-MFMAs while p1 reads drain.

#define STAGE_A(h) do { const unsigned short* g_ = A + gsA + (size_t)(h) * 32;               \
  __builtin_amdgcn_global_load_lds((const __attribute__((address_space(1))) void*)g_,        \
      (__attribute__((address_space(3))) void*)(&sA[(h) & 3][0] + tid * 8), 16, 0, 0);       \
  __builtin_amdgcn_global_load_lds((const __attribute__((address_space(1))) void*)(g_ + (size_t)128 * K), \
      (__attribute__((address_space(3))) void*)(&sA[(h) & 3][4096] + tid * 8), 16, 0, 0); } while (0)
#define STAGE_B(h) do { const unsigned short* g_ = B + gsB + (size_t)(h) * 32;               \
  __builtin_amdgcn_global_load_lds((const __attribute__((address_space(1))) void*)g_,        \
      (__attribute__((address_space(3))) void*)(&sB[(h) & 3][0] + tid * 8), 16, 0, 0);       \
  __builtin_amdgcn_global_load_lds((const __attribute__((address_space(1))) void*)(g_ + (size_t)128 * K), \
      (__attribute__((address_space(3))) void*)(&sB[(h) & 3][4096] + tid * 8), 16, 0, 0); } while (0)

#define LDA(s, m) (*(const bf16x8*)((const char*)&sA[s][0] + offA + (m) * 1024))
#define LDB(s, n) (*(const bf16x8*)((const char*)&sB[s][0] + offB + (n) * 1024))

template <int GELU>
__global__ __launch_bounds__(512, 2) void k_gemm256(const unsigned short* __restrict__ A,
                                                    const unsigned short* __restrict__ B,
                                                    void* __restrict__ C,
                                                    int M, int N, int K) {
  __shared__ __align__(16) unsigned short sA[4][8192];
  __shared__ __align__(16) unsigned short sB[4][8192];
  const int tid = threadIdx.x;
  const int lane = tid & 63;
  const int wave = tid >> 6;
  const int wm = wave >> 2, wn = wave & 3;
  const int r16 = lane & 15, q = lane >> 4;

  // Raster: bijective XCD chunk + grouped-m (GM=16, m-fastest within group).
  const int nbx = N >> 8;
  const int cpx = gridDim.x >> 3;
  const int g = (blockIdx.x & 7) * cpx + (blockIdx.x >> 3);
  const int gw = nbx << 4;
  const int grp = g / gw;
  const int rem = g - grp * gw;
  const int m0 = (grp * 16 + (rem & 15)) * 256;
  const int n0 = (rem >> 4) * 256;

  const int rA = wm * 128 + r16;
  const int rB = wn * 64 + r16;
  const int offA = rA * 64 + ((q * 16) ^ (((rA >> 1) & 3) << 4));
  const int offB = rB * 64 + ((q * 16) ^ (((rB >> 1) & 3) << 4));

  const int sr = tid >> 2;                        // staging row (0..127)
  const int ssrc = (tid & 3) ^ ((sr >> 1) & 3);   // pre-swizzled global 16B slot
  const size_t gsA = (size_t)(m0 + sr) * K + (size_t)ssrc * 8;
  const size_t gsB = (size_t)(n0 + sr) * K + (size_t)ssrc * 8;

  f32x4 acc[8][4] = {};
  bf16x8 pA0[8], pB0[4], pA1[8], pB1[4];
  const int NT = K >> 6;

  // prologue: stage slabs 0,1 (slots 0,1); loop-top sync covers the rest
  STAGE_A(0); STAGE_B(0); STAGE_A(1); STAGE_B(1);

  for (int t = 0; t < NT; ++t) {
    const int s0 = (2 * t) & 3, s1 = (2 * t + 1) & 3;

    // ---- single sync per tile: own-DMA drain, then publish via barrier
    asm volatile("s_waitcnt vmcnt(0)" ::: "memory");
    __builtin_amdgcn_s_barrier();

    // ---- 24 frag reads: slab 2t -> p0, slab 2t+1 -> p1
#pragma unroll
    for (int i = 0; i < 8; ++i) pA0[i] = LDA(s0, i);
#pragma unroll
    for (int j = 0; j < 4; ++j) pB0[j] = LDB(s0, j);
#pragma unroll
    for (int i = 0; i < 8; ++i) pA1[i] = LDA(s1, i);
#pragma unroll
    for (int j = 0; j < 4; ++j) pB1[j] = LDB(s1, j);

    // ---- stage next tile's slabs into the other two ring slots
    if (t < NT - 1) {
      STAGE_A(2 * t + 2); STAGE_B(2 * t + 2);
      STAGE_A(2 * t + 3); STAGE_B(2 * t + 3);
    }

    // ---- 64 MFMA (p0 cluster starts as soon as its 12 reads land)
    __builtin_amdgcn_s_setprio(1);
#pragma unroll
    for (int i = 0; i < 8; ++i)
#pragma unroll
      for (int j = 0; j < 4; ++j)
        acc[i][j] = __builtin_amdgcn_mfma_f32_16x16x32_bf16(pA0[i], pB0[j], acc[i][j], 0, 0, 0);
#pragma unroll
    for (int i = 0; i < 8; ++i)
#pragma unroll
      for (int j = 0; j < 4; ++j)
        acc[i][j] = __builtin_amdgcn_mfma_f32_16x16x32_bf16(pA1[i], pB1[j], acc[i][j], 0, 0, 0);
    __builtin_amdgcn_s_setprio(0);
  }

  // epilogue: C/D layout col=lane&15, row=(lane>>4)*4+reg
  const int mb = m0 + wm * 128 + q * 4;
  const int nb = n0 + wn * 64 + r16;
#pragma unroll
  for (int i = 0; i < 8; ++i) {
#pragma unroll
    for (int j = 0; j < 4; ++j) {
#pragma unroll
      for (int r = 0; r < 4; ++r) {
        int row = mb + i * 16 + r;
        int col = nb + j * 16;
        float v = acc[i][j][r];
        if (GELU) {
          v = 0.5f * v * (1.0f + erff(v * 0.70710678118654752440f));
          ((unsigned short*)C)[(size_t)row * N + col] = f2bf(v);
        } else {
          ((float*)C)[(size_t)row * N + col] = v;
        }
      }
    }
  }
}

extern "C" void kernel_launch(void* const* d_in, const int* in_sizes, int n_in,
                              void* d_out, int out_size, void* d_ws, size_t ws_size,
                              hipStream_t stream) {
  const float* x  = (const float*)d_in[0];
  const int* uqw  = (const int*)d_in[1];
  const int* uqz  = (const int*)d_in[2];
  const float* usc = (const float*)d_in[3];
  const int* dqw  = (const int*)d_in[4];
  const int* dqz  = (const int*)d_in[5];
  const float* dsc = (const float*)d_in[6];
  float* out = (float*)d_out;

  const int T = 8192, D = 4096, F = 16384;
  char* ws = (char*)d_ws;
  unsigned short* xb = (unsigned short*)ws;                                  // 64 MiB
  unsigned short* h  = (unsigned short*)(ws + (size_t)T * D * 2);            // 256 MiB
  unsigned short* wt = (unsigned short*)(ws + (size_t)T * D * 2 + (size_t)T * F * 2); // 128 MiB

  k_f32_to_bf16<<<dim3((T * D) / (256 * 8)), 256, 0, stream>>>(x, xb);
  k_dequant_t<<<dim3(D / 64, F / 64), 256, 0, stream>>>(uqw, uqz, usc, wt, D, F);
  k_gemm256<1><<<dim3((T / 256) * (F / 256)), 512, 0, stream>>>(xb, wt, (void*)h, T, F, D);
  k_dequant_t<<<dim3(F / 64, D / 64), 256, 0, stream>>>(dqw, dqz, dsc, wt, F, D);
  k_gemm256<0><<<dim3((T / 256) * (D / 256)), 512, 0, stream>>>(h, wt, (void*)out, T, D, F);
}